// Round 1
// baseline (1316.555 us; speedup 1.0000x reference)
//
#include <hip/hip_runtime.h>

#define NUu 500000
#define NIi 100000
#define FDIM 300
#define DDIM 64
#define NEe 2000000
#define ELl 1000000

typedef __attribute__((ext_vector_type(8))) short s8v;
typedef __attribute__((ext_vector_type(4))) short s4v;
typedef __attribute__((ext_vector_type(4))) float f4v;
typedef unsigned short u16;

__device__ __forceinline__ float bf2f(u16 h) {
    union { unsigned u; float f; } x; x.u = ((unsigned)h) << 16; return x.f;
}
__device__ __forceinline__ u16 f2bf(float f) {
    union { float f; unsigned u; } x; x.f = f;
    unsigned u = x.u;
    u += 0x7FFFu + ((u >> 16) & 1u);   // round-to-nearest-even
    return (u16)(u >> 16);
}

// ---------------- cast user embeddings (with user_node_id gather) to bf16 ----
__global__ __launch_bounds__(256) void k_cast_users(const float* __restrict__ ue,
                                                    const int* __restrict__ uid,
                                                    u16* __restrict__ xu) {
    int idx = blockIdx.x * 256 + threadIdx.x;   // one thread = 4 elems
    int n  = idx >> 4;
    int d0 = (idx & 15) * 4;
    int src = uid[n];
    const float4* p = (const float4*)(ue + (size_t)src * DDIM + d0);
    float4 v = *p;
    s4v o;
    o[0] = (short)f2bf(v.x); o[1] = (short)f2bf(v.y);
    o[2] = (short)f2bf(v.z); o[3] = (short)f2bf(v.w);
    *(s4v*)(xu + (size_t)n * DDIM + d0) = o;
}

// ---------------- item linear: xi = item_x @ W + b  (SGPR-W, fp32 acc) -------
__global__ __launch_bounds__(256) void k_item_lin(const float* __restrict__ ix,
                                                  const float* __restrict__ W,
                                                  const float* __restrict__ b,
                                                  u16* __restrict__ xi) {
    __shared__ float xt[64][17];
    int tid  = threadIdx.x;
    int lane = tid & 63;
    int dws  = __builtin_amdgcn_readfirstlane((tid >> 6) * 16);
    int base = blockIdx.x * 64;
    float acc[16];
#pragma unroll
    for (int j = 0; j < 16; j++) acc[j] = 0.f;

    for (int kt = 0; kt < 288; kt += 16) {
        __syncthreads();
        for (int idx = tid; idx < 1024; idx += 256) {
            int r = idx >> 4, c2 = idx & 15;
            int row = base + r;
            xt[r][c2] = (row < NIi) ? ix[(size_t)row * FDIM + kt + c2] : 0.f;
        }
        __syncthreads();
#pragma unroll
        for (int kk = 0; kk < 16; kk++) {
            float xv = xt[lane][kk];
            const float* wr = W + (size_t)(kt + kk) * DDIM + dws;
#pragma unroll
            for (int j = 0; j < 16; j++) acc[j] = fmaf(xv, wr[j], acc[j]);
        }
    }
    { // tail kt = 288, kw = 12
        __syncthreads();
        for (int idx = tid; idx < 1024; idx += 256) {
            int r = idx >> 4, c2 = idx & 15;
            int row = base + r;
            float v = 0.f;
            if (row < NIi && (288 + c2) < FDIM) v = ix[(size_t)row * FDIM + 288 + c2];
            xt[r][c2] = v;
        }
        __syncthreads();
#pragma unroll
        for (int kk = 0; kk < 12; kk++) {
            float xv = xt[lane][kk];
            const float* wr = W + (size_t)(288 + kk) * DDIM + dws;
#pragma unroll
            for (int j = 0; j < 16; j++) acc[j] = fmaf(xv, wr[j], acc[j]);
        }
    }
    int n = base + lane;
    if (n < NIi) {
#pragma unroll
        for (int j = 0; j < 16; j++)
            xi[(size_t)n * DDIM + dws + j] = f2bf(acc[j] + b[dws + j]);
    }
}

// ---------------- CSR build ---------------------------------------------------
__global__ __launch_bounds__(256) void k_count(const int* __restrict__ src,
                                               const int* __restrict__ dst,
                                               int* __restrict__ cu, int* __restrict__ ci) {
    int e = blockIdx.x * 256 + threadIdx.x;
    if (e < NEe) {
        atomicAdd(&cu[src[e]], 1);
        atomicAdd(&ci[dst[e]], 1);
    }
}

__global__ __launch_bounds__(256) void k_scanA(const int* __restrict__ cnt, int n,
                                               int* __restrict__ part) {
    __shared__ int sb[256];
    int t = threadIdx.x;
    int base = blockIdx.x * 2048 + t * 8;
    int s = 0;
#pragma unroll
    for (int i = 0; i < 8; i++) { int idx = base + i; if (idx < n) s += cnt[idx]; }
    sb[t] = s; __syncthreads();
    for (int o = 128; o > 0; o >>= 1) { if (t < o) sb[t] += sb[t + o]; __syncthreads(); }
    if (t == 0) part[blockIdx.x] = sb[0];
}

__global__ __launch_bounds__(256) void k_scanB(int* __restrict__ part, int nb,
                                               int* __restrict__ rowptr, int n, int total) {
    __shared__ int sb[256];
    int t = threadIdx.x;
    int v = (t < nb) ? part[t] : 0;
    sb[t] = v; __syncthreads();
    for (int o = 1; o < 256; o <<= 1) {
        int add = (t >= o) ? sb[t - o] : 0;
        __syncthreads();
        sb[t] += add;
        __syncthreads();
    }
    if (t < nb) part[t] = sb[t] - v;     // exclusive
    if (t == 0) rowptr[n] = total;
}

__global__ __launch_bounds__(256) void k_scanC(const int* __restrict__ cnt,
                                               const int* __restrict__ part,
                                               int* __restrict__ rowptr, int n) {
    __shared__ int sb[256];
    int t = threadIdx.x;
    int base = blockIdx.x * 2048 + t * 8;
    int v[8]; int s = 0;
#pragma unroll
    for (int i = 0; i < 8; i++) { int idx = base + i; v[i] = (idx < n) ? cnt[idx] : 0; s += v[i]; }
    sb[t] = s; __syncthreads();
    int tot = s;
    for (int o = 1; o < 256; o <<= 1) {
        int add = (t >= o) ? sb[t - o] : 0;
        __syncthreads();
        sb[t] += add;
        __syncthreads();
    }
    int run = sb[t] - tot + part[blockIdx.x];
#pragma unroll
    for (int i = 0; i < 8; i++) { int idx = base + i; if (idx < n) rowptr[idx] = run; run += v[i]; }
}

__global__ __launch_bounds__(256) void k_fill(const int* __restrict__ src,
                                              const int* __restrict__ dst,
                                              const int* __restrict__ rpu,
                                              const int* __restrict__ rpi,
                                              int* __restrict__ cu, int* __restrict__ ci,
                                              int* __restrict__ colu, int* __restrict__ coli) {
    int e = blockIdx.x * 256 + threadIdx.x;
    if (e < NEe) {
        int s = src[e], d = dst[e];
        int p = atomicAdd(&cu[s], 1); colu[rpu[s] + p] = d;
        int q = atomicAdd(&ci[d], 1); coli[rpi[d] + q] = s;
    }
}

// ---------------- segment-mean aggregation (CSR, bf16 rows) ------------------
__global__ __launch_bounds__(256) void k_agg(const u16* __restrict__ feat,
                                             u16* __restrict__ out,
                                             const int* __restrict__ rp,
                                             const int* __restrict__ col, int n) {
    int lane = threadIdx.x & 63;
    int w = blockIdx.x * 4 + (threadIdx.x >> 6);
    int stride = gridDim.x * 4;
    for (int node = w; node < n; node += stride) {
        int s0 = rp[node], s1 = rp[node + 1];
        float acc = 0.f;
        int j = s0;
        for (; j + 4 <= s1; j += 4) {
            int a = col[j], b = col[j + 1], c = col[j + 2], d = col[j + 3];
            float v0 = bf2f(feat[(size_t)a * DDIM + lane]);
            float v1 = bf2f(feat[(size_t)b * DDIM + lane]);
            float v2 = bf2f(feat[(size_t)c * DDIM + lane]);
            float v3 = bf2f(feat[(size_t)d * DDIM + lane]);
            acc += (v0 + v1) + (v2 + v3);
        }
        for (; j < s1; j++) acc += bf2f(feat[(size_t)col[j] * DDIM + lane]);
        int deg = s1 - s0;
        float sc = deg > 0 ? 1.0f / (float)deg : 0.f;
        out[(size_t)node * DDIM + lane] = f2bf(acc * sc);
    }
}

// ---------------- fused transform: out = [relu](agg@Wl + x@Wr + b), MFMA -----
__global__ __launch_bounds__(256) void k_transform(const u16* __restrict__ aggf,
                                                   const u16* __restrict__ xf,
                                                   const float* __restrict__ Wl,
                                                   const float* __restrict__ Wr,
                                                   const float* __restrict__ bias,
                                                   u16* __restrict__ out,
                                                   int ntiles, int relu) {
    int lane = threadIdx.x & 63;
    int q = lane >> 4, c = lane & 15;
    int w = blockIdx.x * 4 + (threadIdx.x >> 6);
    int stride = gridDim.x * 4;

    s8v wl[2][4], wrg[2][4];
#pragma unroll
    for (int ks = 0; ks < 2; ks++)
#pragma unroll
        for (int nb = 0; nb < 4; nb++) {
            s8v fl, fr;
#pragma unroll
            for (int j = 0; j < 8; j++) {
                int row = ks * 32 + q * 8 + j;
                int cc = nb * 16 + c;
                fl[j] = (short)f2bf(Wl[row * DDIM + cc]);
                fr[j] = (short)f2bf(Wr[row * DDIM + cc]);
            }
            wl[ks][nb] = fl; wrg[ks][nb] = fr;
        }
    float bv[4];
#pragma unroll
    for (int nb = 0; nb < 4; nb++) bv[nb] = bias[nb * 16 + c];

    for (int t = w; t < ntiles; t += stride) {
        const s8v* pa = (const s8v*)(aggf + (size_t)(t * 16 + c) * DDIM + q * 8);
        const s8v* px = (const s8v*)(xf   + (size_t)(t * 16 + c) * DDIM + q * 8);
        s8v a0 = pa[0], a1 = pa[4], x0 = px[0], x1 = px[4];
        f4v acc[4];
#pragma unroll
        for (int nb = 0; nb < 4; nb++) {
            acc[nb][0] = bv[nb]; acc[nb][1] = bv[nb];
            acc[nb][2] = bv[nb]; acc[nb][3] = bv[nb];
        }
#pragma unroll
        for (int nb = 0; nb < 4; nb++) {
            acc[nb] = __builtin_amdgcn_mfma_f32_16x16x32_bf16(a0, wl[0][nb],  acc[nb], 0, 0, 0);
            acc[nb] = __builtin_amdgcn_mfma_f32_16x16x32_bf16(a1, wl[1][nb],  acc[nb], 0, 0, 0);
            acc[nb] = __builtin_amdgcn_mfma_f32_16x16x32_bf16(x0, wrg[0][nb], acc[nb], 0, 0, 0);
            acc[nb] = __builtin_amdgcn_mfma_f32_16x16x32_bf16(x1, wrg[1][nb], acc[nb], 0, 0, 0);
        }
#pragma unroll
        for (int nb = 0; nb < 4; nb++)
#pragma unroll
            for (int r = 0; r < 4; r++) {
                float v = acc[nb][r];
                if (relu) v = fmaxf(v, 0.f);
                out[(size_t)(t * 16 + q * 4 + r) * DDIM + nb * 16 + c] = f2bf(v);
            }
    }
}

// ---------------- final dot predictor ---------------------------------------
__global__ __launch_bounds__(256) void k_dot(const u16* __restrict__ hu,
                                             const u16* __restrict__ hi,
                                             const int* __restrict__ ls,
                                             const int* __restrict__ ld,
                                             float* __restrict__ out) {
    int lane = threadIdx.x & 63;
    int esub = lane >> 4, t4 = lane & 15;
    int w = blockIdx.x * 4 + (threadIdx.x >> 6);
    int stride = gridDim.x * 4;
    const int ngroups = ELl / 4;
    for (int g = w; g < ngroups; g += stride) {
        int e = g * 4 + esub;
        int u = ls[e], it = ld[e];
        s4v av = *(const s4v*)(hu + (size_t)u  * DDIM + t4 * 4);
        s4v bvv = *(const s4v*)(hi + (size_t)it * DDIM + t4 * 4);
        float s = 0.f;
#pragma unroll
        for (int k = 0; k < 4; k++) s += bf2f((u16)av[k]) * bf2f((u16)bvv[k]);
        s += __shfl_xor(s, 8);
        s += __shfl_xor(s, 4);
        s += __shfl_xor(s, 2);
        s += __shfl_xor(s, 1);
        if (t4 == 0) out[e] = s;
    }
}

extern "C" void kernel_launch(void* const* d_in, const int* in_sizes, int n_in,
                              void* d_out, int out_size, void* d_ws, size_t ws_size,
                              hipStream_t stream) {
    const float* user_emb = (const float*)d_in[0];
    const float* item_x   = (const float*)d_in[1];
    const float* item_w   = (const float*)d_in[2];
    const float* item_b   = (const float*)d_in[3];
    const float* Wl1_ui = (const float*)d_in[4];
    const float* Wr1_ui = (const float*)d_in[5];
    const float* b1_ui  = (const float*)d_in[6];
    const float* Wl1_iu = (const float*)d_in[7];
    const float* Wr1_iu = (const float*)d_in[8];
    const float* b1_iu  = (const float*)d_in[9];
    const float* Wl2_ui = (const float*)d_in[10];
    const float* Wr2_ui = (const float*)d_in[11];
    const float* b2_ui  = (const float*)d_in[12];
    const float* Wl2_iu = (const float*)d_in[13];
    const float* Wr2_iu = (const float*)d_in[14];
    const float* b2_iu  = (const float*)d_in[15];
    const int* uid  = (const int*)d_in[16];
    const int* esrc = (const int*)d_in[17];
    const int* edst = (const int*)d_in[18];
    const int* lsrc = (const int*)d_in[19];
    const int* ldst = (const int*)d_in[20];
    float* out = (float*)d_out;

    char* ws = (char*)d_ws;
    size_t off = 0;
    auto alloc = [&](size_t bytes) -> void* {
        void* p = ws + off;
        off += (bytes + 255) & ~(size_t)255;
        return p;
    };
    u16* xu_b   = (u16*)alloc((size_t)NUu * DDIM * 2);
    u16* hu1_b  = (u16*)alloc((size_t)NUu * DDIM * 2);
    u16* aggu_b = (u16*)alloc((size_t)NUu * DDIM * 2);   // also hu2
    u16* xi_b   = (u16*)alloc((size_t)NIi * DDIM * 2);
    u16* hi1_b  = (u16*)alloc((size_t)NIi * DDIM * 2);
    u16* aggi_b = (u16*)alloc((size_t)NIi * DDIM * 2);   // also hi2
    int* coli = (int*)alloc((size_t)NEe * 4);
    int* colu = (int*)alloc((size_t)NEe * 4);
    int* rpi  = (int*)alloc((size_t)(NIi + 1) * 4);
    int* rpu  = (int*)alloc((size_t)(NUu + 1) * 4);
    int* cnti = (int*)alloc((size_t)NIi * 4);
    int* cntu = (int*)alloc((size_t)NUu * 4);
    int* parti = (int*)alloc(1024);
    int* partu = (int*)alloc(1024);

    hipMemsetAsync(cnti, 0, (size_t)NIi * 4, stream);
    hipMemsetAsync(cntu, 0, (size_t)NUu * 4, stream);

    k_cast_users<<<NUu * 16 / 256, 256, 0, stream>>>(user_emb, uid, xu_b);
    k_item_lin<<<(NIi + 63) / 64, 256, 0, stream>>>(item_x, item_w, item_b, xi_b);

    k_count<<<(NEe + 255) / 256, 256, 0, stream>>>(esrc, edst, cntu, cnti);
    int nbi = (NIi + 2047) / 2048;   // 49
    int nbu = (NUu + 2047) / 2048;   // 245
    k_scanA<<<nbi, 256, 0, stream>>>(cnti, NIi, parti);
    k_scanA<<<nbu, 256, 0, stream>>>(cntu, NUu, partu);
    k_scanB<<<1, 256, 0, stream>>>(parti, nbi, rpi, NIi, NEe);
    k_scanB<<<1, 256, 0, stream>>>(partu, nbu, rpu, NUu, NEe);
    k_scanC<<<nbi, 256, 0, stream>>>(cnti, parti, rpi, NIi);
    k_scanC<<<nbu, 256, 0, stream>>>(cntu, partu, rpu, NUu);
    hipMemsetAsync(cnti, 0, (size_t)NIi * 4, stream);
    hipMemsetAsync(cntu, 0, (size_t)NUu * 4, stream);
    k_fill<<<(NEe + 255) / 256, 256, 0, stream>>>(esrc, edst, rpu, rpi, cntu, cnti, colu, coli);

    const int NT_I = NIi / 16;   // 6250
    const int NT_U = NUu / 16;   // 31250

    // layer 1
    k_agg<<<2048, 256, 0, stream>>>(xu_b, aggi_b, rpi, coli, NIi);
    k_transform<<<512, 256, 0, stream>>>(aggi_b, xi_b, Wl1_ui, Wr1_ui, b1_ui, hi1_b, NT_I, 1);
    k_agg<<<2048, 256, 0, stream>>>(xi_b, aggu_b, rpu, colu, NUu);
    k_transform<<<1024, 256, 0, stream>>>(aggu_b, xu_b, Wl1_iu, Wr1_iu, b1_iu, hu1_b, NT_U, 1);

    // layer 2 (hi2 aliases aggi_b, hu2 aliases aggu_b: per-tile read-before-write)
    k_agg<<<2048, 256, 0, stream>>>(hu1_b, aggi_b, rpi, coli, NIi);
    k_transform<<<512, 256, 0, stream>>>(aggi_b, hi1_b, Wl2_ui, Wr2_ui, b2_ui, aggi_b, NT_I, 0);
    k_agg<<<2048, 256, 0, stream>>>(hi1_b, aggu_b, rpu, colu, NUu);
    k_transform<<<1024, 256, 0, stream>>>(aggu_b, hu1_b, Wl2_iu, Wr2_iu, b2_iu, aggu_b, NT_U, 0);

    // predictor
    k_dot<<<2048, 256, 0, stream>>>(aggu_b, aggi_b, lsrc, ldst, out);
}

// Round 2
// 1000.438 us; speedup vs baseline: 1.3160x; 1.3160x over previous
//
#include <hip/hip_runtime.h>

#define NUu 500000
#define NIi 100000
#define FDIM 300
#define DDIM 64
#define NEe 2000000
#define ELl 1000000

// bucket config for CSR build
#define BSZL_I 8      // 256 items per bucket
#define BSZL_U 9      // 512 users per bucket
#define NB_I 391      // ceil(NIi/256)
#define NB_U 977      // ceil(NUu/512)
#define NBT (NB_I + NB_U)   // 1368
#define SH_I 19       // src < 2^19 packed low, d_local<<19
#define SH_U 17       // dst < 2^17 packed low, s_local<<17

typedef __attribute__((ext_vector_type(8))) short s8v;
typedef __attribute__((ext_vector_type(4))) short s4v;
typedef __attribute__((ext_vector_type(4))) float f4v;
typedef unsigned short u16;

__device__ __forceinline__ float bf2f(u16 h) {
    union { unsigned u; float f; } x; x.u = ((unsigned)h) << 16; return x.f;
}
__device__ __forceinline__ u16 f2bf(float f) {
    union { float f; unsigned u; } x; x.f = f;
    unsigned u = x.u;
    u += 0x7FFFu + ((u >> 16) & 1u);   // round-to-nearest-even
    return (u16)(u >> 16);
}

// ---------------- cast user embeddings (with user_node_id gather) to bf16 ----
__global__ __launch_bounds__(256) void k_cast_users(const float* __restrict__ ue,
                                                    const int* __restrict__ uid,
                                                    u16* __restrict__ xu) {
    int idx = blockIdx.x * 256 + threadIdx.x;   // one thread = 4 elems
    int n  = idx >> 4;
    int d0 = (idx & 15) * 4;
    int src = uid[n];
    const float4* p = (const float4*)(ue + (size_t)src * DDIM + d0);
    float4 v = *p;
    s4v o;
    o[0] = (short)f2bf(v.x); o[1] = (short)f2bf(v.y);
    o[2] = (short)f2bf(v.z); o[3] = (short)f2bf(v.w);
    *(s4v*)(xu + (size_t)n * DDIM + d0) = o;
}

// ---------------- item linear: xi = item_x @ W + b  (SGPR-W, fp32 acc) -------
__global__ __launch_bounds__(256) void k_item_lin(const float* __restrict__ ix,
                                                  const float* __restrict__ W,
                                                  const float* __restrict__ b,
                                                  u16* __restrict__ xi) {
    __shared__ float xt[64][17];
    int tid  = threadIdx.x;
    int lane = tid & 63;
    int dws  = __builtin_amdgcn_readfirstlane((tid >> 6) * 16);
    int base = blockIdx.x * 64;
    float acc[16];
#pragma unroll
    for (int j = 0; j < 16; j++) acc[j] = 0.f;

    for (int kt = 0; kt < 288; kt += 16) {
        __syncthreads();
        for (int idx = tid; idx < 1024; idx += 256) {
            int r = idx >> 4, c2 = idx & 15;
            int row = base + r;
            xt[r][c2] = (row < NIi) ? ix[(size_t)row * FDIM + kt + c2] : 0.f;
        }
        __syncthreads();
#pragma unroll
        for (int kk = 0; kk < 16; kk++) {
            float xv = xt[lane][kk];
            const float* wr = W + (size_t)(kt + kk) * DDIM + dws;
#pragma unroll
            for (int j = 0; j < 16; j++) acc[j] = fmaf(xv, wr[j], acc[j]);
        }
    }
    { // tail kt = 288, kw = 12
        __syncthreads();
        for (int idx = tid; idx < 1024; idx += 256) {
            int r = idx >> 4, c2 = idx & 15;
            int row = base + r;
            float v = 0.f;
            if (row < NIi && (288 + c2) < FDIM) v = ix[(size_t)row * FDIM + 288 + c2];
            xt[r][c2] = v;
        }
        __syncthreads();
#pragma unroll
        for (int kk = 0; kk < 12; kk++) {
            float xv = xt[lane][kk];
            const float* wr = W + (size_t)(288 + kk) * DDIM + dws;
#pragma unroll
            for (int j = 0; j < 16; j++) acc[j] = fmaf(xv, wr[j], acc[j]);
        }
    }
    int n = base + lane;
    if (n < NIi) {
#pragma unroll
        for (int j = 0; j < 16; j++)
            xi[(size_t)n * DDIM + dws + j] = f2bf(acc[j] + b[dws + j]);
    }
}

// ---------------- CSR build: bucketed multisplit ------------------------------
// B1: global bucket histogram (LDS-aggregated)
__global__ __launch_bounds__(256) void k_hist(const int* __restrict__ src,
                                              const int* __restrict__ dst,
                                              int* __restrict__ hist) {
    __shared__ int h[NBT];
    int t = threadIdx.x;
    for (int c = t; c < NBT; c += 256) h[c] = 0;
    __syncthreads();
    int base = blockIdx.x * 2048;
#pragma unroll
    for (int k = 0; k < 8; k++) {
        int e = base + k * 256 + t;
        if (e < NEe) {
            int s = src[e], d = dst[e];
            atomicAdd(&h[d >> BSZL_I], 1);
            atomicAdd(&h[NB_I + (s >> BSZL_U)], 1);
        }
    }
    __syncthreads();
    for (int c = t; c < NBT; c += 256) {
        int n = h[c];
        if (n) atomicAdd(&hist[c], n);
    }
}

// B2: single-block exclusive scan of bucket counts (both sides) + frontier copy
__device__ __forceinline__ void scanN(const int* __restrict__ cnt, int n, int total,
                                      int* __restrict__ base, int* __restrict__ frontier,
                                      int* sb) {
    int t = threadIdx.x;
    int v[8]; int s = 0;
#pragma unroll
    for (int i = 0; i < 8; i++) {
        int idx = t * 8 + i;
        v[i] = (idx < n) ? cnt[idx] : 0;
        s += v[i];
    }
    sb[t] = s; __syncthreads();
    for (int o = 1; o < 256; o <<= 1) {
        int a = (t >= o) ? sb[t - o] : 0;
        __syncthreads();
        sb[t] += a;
        __syncthreads();
    }
    int run = sb[t] - s;   // exclusive prefix for this thread's chunk
#pragma unroll
    for (int i = 0; i < 8; i++) {
        int idx = t * 8 + i;
        if (idx < n) { base[idx] = run; frontier[idx] = run; }
        run += v[i];
    }
    if (t == 0) base[n] = total;
    __syncthreads();
}

__global__ __launch_bounds__(256) void k_bucket_scan(const int* __restrict__ hist,
                                                     int* __restrict__ base_i, int* __restrict__ fr_i,
                                                     int* __restrict__ base_u, int* __restrict__ fr_u,
                                                     int* __restrict__ rpi, int* __restrict__ rpu) {
    __shared__ int sb[256];
    scanN(hist, NB_I, NEe, base_i, fr_i, sb);
    scanN(hist + NB_I, NB_U, NEe, base_u, fr_u, sb);
    if (threadIdx.x == 0) { rpi[NIi] = NEe; rpu[NUu] = NEe; }
}

// B3: scatter edges into bucket-ordered arrays (block-aggregated frontiers)
__global__ __launch_bounds__(256) void k_scatter(const int* __restrict__ src,
                                                 const int* __restrict__ dst,
                                                 int* __restrict__ fr_i, int* __restrict__ fr_u,
                                                 unsigned* __restrict__ scat_i,
                                                 unsigned* __restrict__ scat_u) {
    __shared__ int h[NBT];
    int t = threadIdx.x;
    for (int c = t; c < NBT; c += 256) h[c] = 0;
    __syncthreads();
    int base = blockIdx.x * 2048;
#pragma unroll
    for (int k = 0; k < 8; k++) {
        int e = base + k * 256 + t;
        if (e < NEe) {
            int s = src[e], d = dst[e];
            atomicAdd(&h[d >> BSZL_I], 1);
            atomicAdd(&h[NB_I + (s >> BSZL_U)], 1);
        }
    }
    __syncthreads();
    for (int c = t; c < NBT; c += 256) {
        int n = h[c];
        if (n) {
            int b = (c < NB_I) ? atomicAdd(&fr_i[c], n) : atomicAdd(&fr_u[c - NB_I], n);
            h[c] = b;
        }
    }
    __syncthreads();
#pragma unroll
    for (int k = 0; k < 8; k++) {
        int e = base + k * 256 + t;
        if (e < NEe) {
            int s = src[e], d = dst[e];
            int p = atomicAdd(&h[d >> BSZL_I], 1);
            scat_i[p] = (unsigned)s | ((unsigned)(d & 255) << SH_I);
            int q = atomicAdd(&h[NB_I + (s >> BSZL_U)], 1);
            scat_u[q] = (unsigned)d | ((unsigned)(s & 511) << SH_U);
        }
    }
}

// B4: per-bucket CSR fill (one block per bucket; col writes stay in a ~20 KB region)
__global__ __launch_bounds__(256) void k_bfill(const unsigned* __restrict__ scat,
                                               const int* __restrict__ base,
                                               int* __restrict__ rp, int* __restrict__ col,
                                               int shift, int bszlog, int ntotal) {
    __shared__ int cnt[512];
    __shared__ int pos[512];
    __shared__ int sb[256];
    int b = blockIdx.x;
    int t = threadIdx.x;
    int e0 = base[b], e1 = base[b + 1];
    int node0 = b << bszlog;
    int bsz = 1 << bszlog;
    unsigned mask = (1u << shift) - 1u;

    for (int c = t; c < bsz; c += 256) cnt[c] = 0;
    __syncthreads();
    for (int e = e0 + t; e < e1; e += 256) {
        unsigned v = scat[e];
        atomicAdd(&cnt[v >> shift], 1);
    }
    __syncthreads();
    // exclusive scan of cnt[0..bsz)
    int per = bsz >> 8;   // 1 or 2 elems per thread
    int loc[2]; int ls = 0;
#pragma unroll
    for (int i = 0; i < 2; i++) {
        loc[i] = (i < per) ? cnt[t * per + i] : 0;
        ls += loc[i];
    }
    sb[t] = ls; __syncthreads();
    for (int o = 1; o < 256; o <<= 1) {
        int a = (t >= o) ? sb[t - o] : 0;
        __syncthreads();
        sb[t] += a;
        __syncthreads();
    }
    int run = e0 + sb[t] - ls;
#pragma unroll
    for (int i = 0; i < 2; i++) {
        if (i < per) {
            int idx = t * per + i;
            int node = node0 + idx;
            if (node < ntotal) rp[node] = run;
            pos[idx] = run;
            run += loc[i];
        }
    }
    __syncthreads();
    for (int e = e0 + t; e < e1; e += 256) {
        unsigned v = scat[e];
        int l = v >> shift;
        int p = atomicAdd(&pos[l], 1);
        col[p] = (int)(v & mask);
    }
}

// ---------------- segment-mean aggregation (CSR, 4 rows per wave load) -------
__global__ __launch_bounds__(256) void k_agg(const u16* __restrict__ feat,
                                             u16* __restrict__ out,
                                             const int* __restrict__ rp,
                                             const int* __restrict__ col, int n) {
    int lane = threadIdx.x & 63;
    int g = lane >> 4;        // neighbor sub-slot 0..3
    int t = lane & 15;        // channel quarter: channels t*4..t*4+3
    int w = blockIdx.x * 4 + (threadIdx.x >> 6);
    int stride = gridDim.x * 4;
    for (int node = w; node < n; node += stride) {
        int s0 = rp[node], s1 = rp[node + 1];
        float a0 = 0.f, a1 = 0.f, a2 = 0.f, a3 = 0.f;
        int j = s0 + g;
        for (; j + 4 < s1; j += 8) {
            int r0 = col[j], r1 = col[j + 4];
            s4v v0 = *(const s4v*)(feat + (size_t)r0 * DDIM + t * 4);
            s4v v1 = *(const s4v*)(feat + (size_t)r1 * DDIM + t * 4);
            a0 += bf2f((u16)v0[0]) + bf2f((u16)v1[0]);
            a1 += bf2f((u16)v0[1]) + bf2f((u16)v1[1]);
            a2 += bf2f((u16)v0[2]) + bf2f((u16)v1[2]);
            a3 += bf2f((u16)v0[3]) + bf2f((u16)v1[3]);
        }
        if (j < s1) {
            int r = col[j];
            s4v v = *(const s4v*)(feat + (size_t)r * DDIM + t * 4);
            a0 += bf2f((u16)v[0]); a1 += bf2f((u16)v[1]);
            a2 += bf2f((u16)v[2]); a3 += bf2f((u16)v[3]);
        }
        // combine the 4 neighbor sub-slots
        a0 += __shfl_xor(a0, 16); a0 += __shfl_xor(a0, 32);
        a1 += __shfl_xor(a1, 16); a1 += __shfl_xor(a1, 32);
        a2 += __shfl_xor(a2, 16); a2 += __shfl_xor(a2, 32);
        a3 += __shfl_xor(a3, 16); a3 += __shfl_xor(a3, 32);
        if (g == 0) {
            int deg = s1 - s0;
            float sc = deg > 0 ? 1.0f / (float)deg : 0.f;
            s4v o;
            o[0] = (short)f2bf(a0 * sc); o[1] = (short)f2bf(a1 * sc);
            o[2] = (short)f2bf(a2 * sc); o[3] = (short)f2bf(a3 * sc);
            *(s4v*)(out + (size_t)node * DDIM + t * 4) = o;
        }
    }
}

// ---------------- fused transform: out = [relu](agg@Wl + x@Wr + b), MFMA -----
__global__ __launch_bounds__(256) void k_transform(const u16* __restrict__ aggf,
                                                   const u16* __restrict__ xf,
                                                   const float* __restrict__ Wl,
                                                   const float* __restrict__ Wr,
                                                   const float* __restrict__ bias,
                                                   u16* __restrict__ out,
                                                   int ntiles, int relu) {
    int lane = threadIdx.x & 63;
    int q = lane >> 4, c = lane & 15;
    int w = blockIdx.x * 4 + (threadIdx.x >> 6);
    int stride = gridDim.x * 4;

    s8v wl[2][4], wrg[2][4];
#pragma unroll
    for (int ks = 0; ks < 2; ks++)
#pragma unroll
        for (int nb = 0; nb < 4; nb++) {
            s8v fl, fr;
#pragma unroll
            for (int j = 0; j < 8; j++) {
                int row = ks * 32 + q * 8 + j;
                int cc = nb * 16 + c;
                fl[j] = (short)f2bf(Wl[row * DDIM + cc]);
                fr[j] = (short)f2bf(Wr[row * DDIM + cc]);
            }
            wl[ks][nb] = fl; wrg[ks][nb] = fr;
        }
    float bv[4];
#pragma unroll
    for (int nb = 0; nb < 4; nb++) bv[nb] = bias[nb * 16 + c];

    for (int t = w; t < ntiles; t += stride) {
        const s8v* pa = (const s8v*)(aggf + (size_t)(t * 16 + c) * DDIM + q * 8);
        const s8v* px = (const s8v*)(xf   + (size_t)(t * 16 + c) * DDIM + q * 8);
        s8v a0 = pa[0], a1 = pa[4], x0 = px[0], x1 = px[4];
        f4v acc[4];
#pragma unroll
        for (int nb = 0; nb < 4; nb++) {
            acc[nb][0] = bv[nb]; acc[nb][1] = bv[nb];
            acc[nb][2] = bv[nb]; acc[nb][3] = bv[nb];
        }
#pragma unroll
        for (int nb = 0; nb < 4; nb++) {
            acc[nb] = __builtin_amdgcn_mfma_f32_16x16x32_bf16(a0, wl[0][nb],  acc[nb], 0, 0, 0);
            acc[nb] = __builtin_amdgcn_mfma_f32_16x16x32_bf16(a1, wl[1][nb],  acc[nb], 0, 0, 0);
            acc[nb] = __builtin_amdgcn_mfma_f32_16x16x32_bf16(x0, wrg[0][nb], acc[nb], 0, 0, 0);
            acc[nb] = __builtin_amdgcn_mfma_f32_16x16x32_bf16(x1, wrg[1][nb], acc[nb], 0, 0, 0);
        }
#pragma unroll
        for (int nb = 0; nb < 4; nb++)
#pragma unroll
            for (int r = 0; r < 4; r++) {
                float v = acc[nb][r];
                if (relu) v = fmaxf(v, 0.f);
                out[(size_t)(t * 16 + q * 4 + r) * DDIM + nb * 16 + c] = f2bf(v);
            }
    }
}

// ---------------- final dot predictor (8 edges per wave, 16 B/lane) ----------
__global__ __launch_bounds__(256) void k_dot(const u16* __restrict__ hu,
                                             const u16* __restrict__ hi,
                                             const int* __restrict__ ls,
                                             const int* __restrict__ ld,
                                             float* __restrict__ out) {
    int lane = threadIdx.x & 63;
    int sub = lane >> 3, t8 = lane & 7;
    int w = blockIdx.x * 4 + (threadIdx.x >> 6);
    int stride = gridDim.x * 4;
    const int ngroups = ELl / 8;
    for (int g = w; g < ngroups; g += stride) {
        int e = g * 8 + sub;
        int u = ls[e], it = ld[e];
        s8v av = *(const s8v*)(hu + (size_t)u  * DDIM + t8 * 8);
        s8v bv = *(const s8v*)(hi + (size_t)it * DDIM + t8 * 8);
        float s = 0.f;
#pragma unroll
        for (int k = 0; k < 8; k++) s += bf2f((u16)av[k]) * bf2f((u16)bv[k]);
        s += __shfl_xor(s, 4);
        s += __shfl_xor(s, 2);
        s += __shfl_xor(s, 1);
        if (t8 == 0) out[e] = s;
    }
}

extern "C" void kernel_launch(void* const* d_in, const int* in_sizes, int n_in,
                              void* d_out, int out_size, void* d_ws, size_t ws_size,
                              hipStream_t stream) {
    const float* user_emb = (const float*)d_in[0];
    const float* item_x   = (const float*)d_in[1];
    const float* item_w   = (const float*)d_in[2];
    const float* item_b   = (const float*)d_in[3];
    const float* Wl1_ui = (const float*)d_in[4];
    const float* Wr1_ui = (const float*)d_in[5];
    const float* b1_ui  = (const float*)d_in[6];
    const float* Wl1_iu = (const float*)d_in[7];
    const float* Wr1_iu = (const float*)d_in[8];
    const float* b1_iu  = (const float*)d_in[9];
    const float* Wl2_ui = (const float*)d_in[10];
    const float* Wr2_ui = (const float*)d_in[11];
    const float* b2_ui  = (const float*)d_in[12];
    const float* Wl2_iu = (const float*)d_in[13];
    const float* Wr2_iu = (const float*)d_in[14];
    const float* b2_iu  = (const float*)d_in[15];
    const int* uid  = (const int*)d_in[16];
    const int* esrc = (const int*)d_in[17];
    const int* edst = (const int*)d_in[18];
    const int* lsrc = (const int*)d_in[19];
    const int* ldst = (const int*)d_in[20];
    float* out = (float*)d_out;

    char* ws = (char*)d_ws;
    size_t off = 0;
    auto alloc = [&](size_t bytes) -> void* {
        void* p = ws + off;
        off += (bytes + 255) & ~(size_t)255;
        return p;
    };
    u16* xu_b   = (u16*)alloc((size_t)NUu * DDIM * 2);
    u16* hu1_b  = (u16*)alloc((size_t)NUu * DDIM * 2);
    u16* aggu_b = (u16*)alloc((size_t)NUu * DDIM * 2);   // also hu2
    u16* xi_b   = (u16*)alloc((size_t)NIi * DDIM * 2);
    u16* hi1_b  = (u16*)alloc((size_t)NIi * DDIM * 2);
    u16* aggi_b = (u16*)alloc((size_t)NIi * DDIM * 2);   // also hi2
    int* coli = (int*)alloc((size_t)NEe * 4);
    int* colu = (int*)alloc((size_t)NEe * 4);
    int* rpi  = (int*)alloc((size_t)(NIi + 1) * 4);
    int* rpu  = (int*)alloc((size_t)(NUu + 1) * 4);
    int* hist   = (int*)alloc((size_t)NBT * 4);
    int* base_i = (int*)alloc((size_t)(NB_I + 1) * 4);
    int* base_u = (int*)alloc((size_t)(NB_U + 1) * 4);
    int* fr_i   = (int*)alloc((size_t)NB_I * 4);
    int* fr_u   = (int*)alloc((size_t)NB_U * 4);
    // scatter buffers alias xu_b (16 MB < 64 MB): CSR build runs before k_cast_users
    unsigned* scat_i = (unsigned*)xu_b;
    unsigned* scat_u = (unsigned*)((char*)xu_b + (size_t)NEe * 4);

    // ---- CSR build (bucketed) ----
    hipMemsetAsync(hist, 0, (size_t)NBT * 4, stream);
    int nchunks = (NEe + 2047) / 2048;   // 977
    k_hist<<<nchunks, 256, 0, stream>>>(esrc, edst, hist);
    k_bucket_scan<<<1, 256, 0, stream>>>(hist, base_i, fr_i, base_u, fr_u, rpi, rpu);
    k_scatter<<<nchunks, 256, 0, stream>>>(esrc, edst, fr_i, fr_u, scat_i, scat_u);
    k_bfill<<<NB_I, 256, 0, stream>>>(scat_i, base_i, rpi, coli, SH_I, BSZL_I, NIi);
    k_bfill<<<NB_U, 256, 0, stream>>>(scat_u, base_u, rpu, colu, SH_U, BSZL_U, NUu);

    // ---- input features (after CSR build: scat_* alias xu_b) ----
    k_cast_users<<<NUu * 16 / 256, 256, 0, stream>>>(user_emb, uid, xu_b);
    k_item_lin<<<(NIi + 63) / 64, 256, 0, stream>>>(item_x, item_w, item_b, xi_b);

    const int NT_I = NIi / 16;   // 6250
    const int NT_U = NUu / 16;   // 31250

    // layer 1
    k_agg<<<2048, 256, 0, stream>>>(xu_b, aggi_b, rpi, coli, NIi);
    k_transform<<<512, 256, 0, stream>>>(aggi_b, xi_b, Wl1_ui, Wr1_ui, b1_ui, hi1_b, NT_I, 1);
    k_agg<<<2048, 256, 0, stream>>>(xi_b, aggu_b, rpu, colu, NUu);
    k_transform<<<1024, 256, 0, stream>>>(aggu_b, xu_b, Wl1_iu, Wr1_iu, b1_iu, hu1_b, NT_U, 1);

    // layer 2 (hi2 aliases aggi_b, hu2 aliases aggu_b: per-tile read-before-write)
    k_agg<<<2048, 256, 0, stream>>>(hu1_b, aggi_b, rpi, coli, NIi);
    k_transform<<<512, 256, 0, stream>>>(aggi_b, hi1_b, Wl2_ui, Wr2_ui, b2_ui, aggi_b, NT_I, 0);
    k_agg<<<2048, 256, 0, stream>>>(hi1_b, aggu_b, rpu, colu, NUu);
    k_transform<<<1024, 256, 0, stream>>>(aggu_b, hu1_b, Wl2_iu, Wr2_iu, b2_iu, aggu_b, NT_U, 0);

    // predictor
    k_dot<<<2048, 256, 0, stream>>>(aggu_b, aggi_b, lsrc, ldst, out);
}

// Round 3
// 908.645 us; speedup vs baseline: 1.4489x; 1.1010x over previous
//
#include <hip/hip_runtime.h>

#define NUu 500000
#define NIi 100000
#define FDIM 300
#define DDIM 64
#define NEe 2000000
#define ELl 1000000

// bucket config for CSR build
#define BSZL_I 8      // 256 items per bucket
#define BSZL_U 9      // 512 users per bucket
#define NB_I 391      // ceil(NIi/256)
#define NB_U 977      // ceil(NUu/512)
#define NBT (NB_I + NB_U)   // 1368
#define SH_I 19       // src < 2^19 packed low, d_local<<19
#define SH_U 17       // dst < 2^17 packed low, s_local<<17

typedef __attribute__((ext_vector_type(8))) short s8v;
typedef __attribute__((ext_vector_type(4))) short s4v;
typedef __attribute__((ext_vector_type(4))) float f4v;
typedef unsigned short u16;

__device__ __forceinline__ float bf2f(u16 h) {
    union { unsigned u; float f; } x; x.u = ((unsigned)h) << 16; return x.f;
}
__device__ __forceinline__ u16 f2bf(float f) {
    union { float f; unsigned u; } x; x.f = f;
    unsigned u = x.u;
    u += 0x7FFFu + ((u >> 16) & 1u);   // round-to-nearest-even
    return (u16)(u >> 16);
}

// ---------------- cast user embeddings (with user_node_id gather) to bf16 ----
__global__ __launch_bounds__(256) void k_cast_users(const float* __restrict__ ue,
                                                    const int* __restrict__ uid,
                                                    u16* __restrict__ xu) {
    int idx = blockIdx.x * 256 + threadIdx.x;   // one thread = 4 elems
    int n  = idx >> 4;
    int d0 = (idx & 15) * 4;
    int src = uid[n];
    const float4* p = (const float4*)(ue + (size_t)src * DDIM + d0);
    float4 v = *p;
    s4v o;
    o[0] = (short)f2bf(v.x); o[1] = (short)f2bf(v.y);
    o[2] = (short)f2bf(v.z); o[3] = (short)f2bf(v.w);
    *(s4v*)(xu + (size_t)n * DDIM + d0) = o;
}

// ---------------- cast item_lin_w to bf16 in MFMA B-fragment order ----------
// frag f = kstep*4 + nb (kstep 0..9, nb 0..3); within frag, lane (q=lane>>4,
// c=lane&15) holds B[k=kstep*32+q*8+j][nb*16+c], j=0..7; zero-pad k>=300.
__global__ __launch_bounds__(256) void k_cast_w(const float* __restrict__ W,
                                                u16* __restrict__ wbf) {
    int idx = blockIdx.x * 256 + threadIdx.x;   // 2560 lane-slots
    if (idx >= 2560) return;
    int f = idx >> 6, lane = idx & 63;
    int q = lane >> 4, c = lane & 15;
    int kstep = f >> 2, nb = f & 3;
    u16* dst = wbf + (size_t)idx * 8;
#pragma unroll
    for (int j = 0; j < 8; j++) {
        int k = kstep * 32 + q * 8 + j;
        float v = (k < FDIM) ? W[k * DDIM + nb * 16 + c] : 0.f;
        dst[j] = f2bf(v);
    }
}

// ---------------- item linear via MFMA: xi = item_x @ W + b ------------------
__global__ __launch_bounds__(256) void k_item_lin2(const float* __restrict__ ix,
                                                   const u16* __restrict__ wbf,
                                                   const float* __restrict__ b,
                                                   u16* __restrict__ xi) {
    __shared__ __align__(16) u16 wl[40 * 64 * 8];   // 40960 B
    int tid = threadIdx.x;
    for (int i = tid; i < 2560; i += 256)
        ((f4v*)wl)[i] = ((const f4v*)wbf)[i];
    __syncthreads();

    int lane = tid & 63;
    int q = lane >> 4, c = lane & 15;
    float bv[4];
#pragma unroll
    for (int nb = 0; nb < 4; nb++) bv[nb] = b[nb * 16 + c];

    int w = blockIdx.x * 4 + (tid >> 6);
    int stride = gridDim.x * 4;
    const int NT = NIi / 16;   // 6250
    for (int t = w; t < NT; t += stride) {
        int row = t * 16 + c;
        const float* xr = ix + (size_t)row * FDIM;
        f4v acc[4];
#pragma unroll
        for (int nb = 0; nb < 4; nb++) {
            acc[nb][0] = bv[nb]; acc[nb][1] = bv[nb];
            acc[nb][2] = bv[nb]; acc[nb][3] = bv[nb];
        }
#pragma unroll
        for (int ks = 0; ks < 10; ks++) {
            s8v a;
            if (ks < 9 || q == 0) {
                float4 v0 = *(const float4*)(xr + ks * 32 + q * 8);
                float4 v1 = *(const float4*)(xr + ks * 32 + q * 8 + 4);
                a[0] = (short)f2bf(v0.x); a[1] = (short)f2bf(v0.y);
                a[2] = (short)f2bf(v0.z); a[3] = (short)f2bf(v0.w);
                a[4] = (short)f2bf(v1.x); a[5] = (short)f2bf(v1.y);
                a[6] = (short)f2bf(v1.z); a[7] = (short)f2bf(v1.w);
            } else {   // ks==9, q==1: k = 296..303, valid only 296..299
                float4 v0 = *(const float4*)(xr + 296);
                a[0] = (short)f2bf(v0.x); a[1] = (short)f2bf(v0.y);
                a[2] = (short)f2bf(v0.z); a[3] = (short)f2bf(v0.w);
                a[4] = 0; a[5] = 0; a[6] = 0; a[7] = 0;
            }
#pragma unroll
            for (int nb = 0; nb < 4; nb++) {
                s8v bb = *(const s8v*)(wl + ((size_t)(ks * 4 + nb) * 64 + lane) * 8);
                acc[nb] = __builtin_amdgcn_mfma_f32_16x16x32_bf16(a, bb, acc[nb], 0, 0, 0);
            }
        }
#pragma unroll
        for (int nb = 0; nb < 4; nb++)
#pragma unroll
            for (int r = 0; r < 4; r++)
                xi[(size_t)(t * 16 + q * 4 + r) * DDIM + nb * 16 + c] = f2bf(acc[nb][r]);
    }
}

// ---------------- CSR build: bucketed multisplit ------------------------------
__global__ __launch_bounds__(256) void k_hist(const int* __restrict__ src,
                                              const int* __restrict__ dst,
                                              int* __restrict__ hist) {
    __shared__ int h[NBT];
    int t = threadIdx.x;
    for (int c = t; c < NBT; c += 256) h[c] = 0;
    __syncthreads();
    int base = blockIdx.x * 2048;
#pragma unroll
    for (int k = 0; k < 8; k++) {
        int e = base + k * 256 + t;
        if (e < NEe) {
            int s = src[e], d = dst[e];
            atomicAdd(&h[d >> BSZL_I], 1);
            atomicAdd(&h[NB_I + (s >> BSZL_U)], 1);
        }
    }
    __syncthreads();
    for (int c = t; c < NBT; c += 256) {
        int n = h[c];
        if (n) atomicAdd(&hist[c], n);
    }
}

__device__ __forceinline__ void scanN(const int* __restrict__ cnt, int n, int total,
                                      int* __restrict__ base, int* __restrict__ frontier,
                                      int* sb) {
    int t = threadIdx.x;
    int v[8]; int s = 0;
#pragma unroll
    for (int i = 0; i < 8; i++) {
        int idx = t * 8 + i;
        v[i] = (idx < n) ? cnt[idx] : 0;
        s += v[i];
    }
    sb[t] = s; __syncthreads();
    for (int o = 1; o < 256; o <<= 1) {
        int a = (t >= o) ? sb[t - o] : 0;
        __syncthreads();
        sb[t] += a;
        __syncthreads();
    }
    int run = sb[t] - s;
#pragma unroll
    for (int i = 0; i < 8; i++) {
        int idx = t * 8 + i;
        if (idx < n) { base[idx] = run; frontier[idx] = run; }
        run += v[i];
    }
    if (t == 0) base[n] = total;
    __syncthreads();
}

__global__ __launch_bounds__(256) void k_bucket_scan(const int* __restrict__ hist,
                                                     int* __restrict__ base_i, int* __restrict__ fr_i,
                                                     int* __restrict__ base_u, int* __restrict__ fr_u,
                                                     int* __restrict__ rpi, int* __restrict__ rpu) {
    __shared__ int sb[256];
    scanN(hist, NB_I, NEe, base_i, fr_i, sb);
    scanN(hist + NB_I, NB_U, NEe, base_u, fr_u, sb);
    if (threadIdx.x == 0) { rpi[NIi] = NEe; rpu[NUu] = NEe; }
}

__global__ __launch_bounds__(256) void k_scatter(const int* __restrict__ src,
                                                 const int* __restrict__ dst,
                                                 int* __restrict__ fr_i, int* __restrict__ fr_u,
                                                 unsigned* __restrict__ scat_i,
                                                 unsigned* __restrict__ scat_u) {
    __shared__ int h[NBT];
    int t = threadIdx.x;
    for (int c = t; c < NBT; c += 256) h[c] = 0;
    __syncthreads();
    int base = blockIdx.x * 2048;
#pragma unroll
    for (int k = 0; k < 8; k++) {
        int e = base + k * 256 + t;
        if (e < NEe) {
            int s = src[e], d = dst[e];
            atomicAdd(&h[d >> BSZL_I], 1);
            atomicAdd(&h[NB_I + (s >> BSZL_U)], 1);
        }
    }
    __syncthreads();
    for (int c = t; c < NBT; c += 256) {
        int n = h[c];
        if (n) {
            int b = (c < NB_I) ? atomicAdd(&fr_i[c], n) : atomicAdd(&fr_u[c - NB_I], n);
            h[c] = b;
        }
    }
    __syncthreads();
#pragma unroll
    for (int k = 0; k < 8; k++) {
        int e = base + k * 256 + t;
        if (e < NEe) {
            int s = src[e], d = dst[e];
            int p = atomicAdd(&h[d >> BSZL_I], 1);
            scat_i[p] = (unsigned)s | ((unsigned)(d & 255) << SH_I);
            int q = atomicAdd(&h[NB_I + (s >> BSZL_U)], 1);
            scat_u[q] = (unsigned)d | ((unsigned)(s & 511) << SH_U);
        }
    }
}

__global__ __launch_bounds__(256) void k_bfill(const unsigned* __restrict__ scat,
                                               const int* __restrict__ base,
                                               int* __restrict__ rp, int* __restrict__ col,
                                               int shift, int bszlog, int ntotal) {
    __shared__ int cnt[512];
    __shared__ int pos[512];
    __shared__ int sb[256];
    int b = blockIdx.x;
    int t = threadIdx.x;
    int e0 = base[b], e1 = base[b + 1];
    int node0 = b << bszlog;
    int bsz = 1 << bszlog;
    unsigned mask = (1u << shift) - 1u;

    for (int c = t; c < bsz; c += 256) cnt[c] = 0;
    __syncthreads();
    for (int e = e0 + t; e < e1; e += 256) {
        unsigned v = scat[e];
        atomicAdd(&cnt[v >> shift], 1);
    }
    __syncthreads();
    int per = bsz >> 8;
    int loc[2]; int ls = 0;
#pragma unroll
    for (int i = 0; i < 2; i++) {
        loc[i] = (i < per) ? cnt[t * per + i] : 0;
        ls += loc[i];
    }
    sb[t] = ls; __syncthreads();
    for (int o = 1; o < 256; o <<= 1) {
        int a = (t >= o) ? sb[t - o] : 0;
        __syncthreads();
        sb[t] += a;
        __syncthreads();
    }
    int run = e0 + sb[t] - ls;
#pragma unroll
    for (int i = 0; i < 2; i++) {
        if (i < per) {
            int idx = t * per + i;
            int node = node0 + idx;
            if (node < ntotal) rp[node] = run;
            pos[idx] = run;
            run += loc[i];
        }
    }
    __syncthreads();
    for (int e = e0 + t; e < e1; e += 256) {
        unsigned v = scat[e];
        int l = v >> shift;
        int p = atomicAdd(&pos[l], 1);
        col[p] = (int)(v & mask);
    }
}

// ---------------- segment-mean aggregation (CSR, 4 rows per wave load) -------
__global__ __launch_bounds__(256) void k_agg(const u16* __restrict__ feat,
                                             u16* __restrict__ out,
                                             const int* __restrict__ rp,
                                             const int* __restrict__ col, int n) {
    int lane = threadIdx.x & 63;
    int g = lane >> 4;
    int t = lane & 15;
    int w = blockIdx.x * 4 + (threadIdx.x >> 6);
    int stride = gridDim.x * 4;
    for (int node = w; node < n; node += stride) {
        int s0 = rp[node], s1 = rp[node + 1];
        float a0 = 0.f, a1 = 0.f, a2 = 0.f, a3 = 0.f;
        int j = s0 + g;
        for (; j + 4 < s1; j += 8) {
            int r0 = col[j], r1 = col[j + 4];
            s4v v0 = *(const s4v*)(feat + (size_t)r0 * DDIM + t * 4);
            s4v v1 = *(const s4v*)(feat + (size_t)r1 * DDIM + t * 4);
            a0 += bf2f((u16)v0[0]) + bf2f((u16)v1[0]);
            a1 += bf2f((u16)v0[1]) + bf2f((u16)v1[1]);
            a2 += bf2f((u16)v0[2]) + bf2f((u16)v1[2]);
            a3 += bf2f((u16)v0[3]) + bf2f((u16)v1[3]);
        }
        if (j < s1) {
            int r = col[j];
            s4v v = *(const s4v*)(feat + (size_t)r * DDIM + t * 4);
            a0 += bf2f((u16)v[0]); a1 += bf2f((u16)v[1]);
            a2 += bf2f((u16)v[2]); a3 += bf2f((u16)v[3]);
        }
        a0 += __shfl_xor(a0, 16); a0 += __shfl_xor(a0, 32);
        a1 += __shfl_xor(a1, 16); a1 += __shfl_xor(a1, 32);
        a2 += __shfl_xor(a2, 16); a2 += __shfl_xor(a2, 32);
        a3 += __shfl_xor(a3, 16); a3 += __shfl_xor(a3, 32);
        if (g == 0) {
            int deg = s1 - s0;
            float sc = deg > 0 ? 1.0f / (float)deg : 0.f;
            s4v o;
            o[0] = (short)f2bf(a0 * sc); o[1] = (short)f2bf(a1 * sc);
            o[2] = (short)f2bf(a2 * sc); o[3] = (short)f2bf(a3 * sc);
            *(s4v*)(out + (size_t)node * DDIM + t * 4) = o;
        }
    }
}

// ---------------- fused transform: out = [relu](agg@Wl + x@Wr + b), MFMA -----
__global__ __launch_bounds__(256) void k_transform(const u16* __restrict__ aggf,
                                                   const u16* __restrict__ xf,
                                                   const float* __restrict__ Wl,
                                                   const float* __restrict__ Wr,
                                                   const float* __restrict__ bias,
                                                   u16* __restrict__ out,
                                                   int ntiles, int relu) {
    int lane = threadIdx.x & 63;
    int q = lane >> 4, c = lane & 15;
    int w = blockIdx.x * 4 + (threadIdx.x >> 6);
    int stride = gridDim.x * 4;

    s8v wl[2][4], wrg[2][4];
#pragma unroll
    for (int ks = 0; ks < 2; ks++)
#pragma unroll
        for (int nb = 0; nb < 4; nb++) {
            s8v fl, fr;
#pragma unroll
            for (int j = 0; j < 8; j++) {
                int row = ks * 32 + q * 8 + j;
                int cc = nb * 16 + c;
                fl[j] = (short)f2bf(Wl[row * DDIM + cc]);
                fr[j] = (short)f2bf(Wr[row * DDIM + cc]);
            }
            wl[ks][nb] = fl; wrg[ks][nb] = fr;
        }
    float bv[4];
#pragma unroll
    for (int nb = 0; nb < 4; nb++) bv[nb] = bias[nb * 16 + c];

    for (int t = w; t < ntiles; t += stride) {
        const s8v* pa = (const s8v*)(aggf + (size_t)(t * 16 + c) * DDIM + q * 8);
        const s8v* px = (const s8v*)(xf   + (size_t)(t * 16 + c) * DDIM + q * 8);
        s8v a0 = pa[0], a1 = pa[4], x0 = px[0], x1 = px[4];
        f4v acc[4];
#pragma unroll
        for (int nb = 0; nb < 4; nb++) {
            acc[nb][0] = bv[nb]; acc[nb][1] = bv[nb];
            acc[nb][2] = bv[nb]; acc[nb][3] = bv[nb];
        }
#pragma unroll
        for (int nb = 0; nb < 4; nb++) {
            acc[nb] = __builtin_amdgcn_mfma_f32_16x16x32_bf16(a0, wl[0][nb],  acc[nb], 0, 0, 0);
            acc[nb] = __builtin_amdgcn_mfma_f32_16x16x32_bf16(a1, wl[1][nb],  acc[nb], 0, 0, 0);
            acc[nb] = __builtin_amdgcn_mfma_f32_16x16x32_bf16(x0, wrg[0][nb], acc[nb], 0, 0, 0);
            acc[nb] = __builtin_amdgcn_mfma_f32_16x16x32_bf16(x1, wrg[1][nb], acc[nb], 0, 0, 0);
        }
#pragma unroll
        for (int nb = 0; nb < 4; nb++)
#pragma unroll
            for (int r = 0; r < 4; r++) {
                float v = acc[nb][r];
                if (relu) v = fmaxf(v, 0.f);
                out[(size_t)(t * 16 + q * 4 + r) * DDIM + nb * 16 + c] = f2bf(v);
            }
    }
}

// ---------------- final dot predictor (8 edges per wave, 16 B/lane) ----------
__global__ __launch_bounds__(256) void k_dot(const u16* __restrict__ hu,
                                             const u16* __restrict__ hi,
                                             const int* __restrict__ ls,
                                             const int* __restrict__ ld,
                                             float* __restrict__ out) {
    int lane = threadIdx.x & 63;
    int sub = lane >> 3, t8 = lane & 7;
    int w = blockIdx.x * 4 + (threadIdx.x >> 6);
    int stride = gridDim.x * 4;
    const int ngroups = ELl / 8;
    for (int g = w; g < ngroups; g += stride) {
        int e = g * 8 + sub;
        int u = ls[e], it = ld[e];
        s8v av = *(const s8v*)(hu + (size_t)u  * DDIM + t8 * 8);
        s8v bv = *(const s8v*)(hi + (size_t)it * DDIM + t8 * 8);
        float s = 0.f;
#pragma unroll
        for (int k = 0; k < 8; k++) s += bf2f((u16)av[k]) * bf2f((u16)bv[k]);
        s += __shfl_xor(s, 4);
        s += __shfl_xor(s, 2);
        s += __shfl_xor(s, 1);
        if (t8 == 0) out[e] = s;
    }
}

extern "C" void kernel_launch(void* const* d_in, const int* in_sizes, int n_in,
                              void* d_out, int out_size, void* d_ws, size_t ws_size,
                              hipStream_t stream) {
    const float* user_emb = (const float*)d_in[0];
    const float* item_x   = (const float*)d_in[1];
    const float* item_w   = (const float*)d_in[2];
    const float* item_b   = (const float*)d_in[3];
    const float* Wl1_ui = (const float*)d_in[4];
    const float* Wr1_ui = (const float*)d_in[5];
    const float* b1_ui  = (const float*)d_in[6];
    const float* Wl1_iu = (const float*)d_in[7];
    const float* Wr1_iu = (const float*)d_in[8];
    const float* b1_iu  = (const float*)d_in[9];
    const float* Wl2_ui = (const float*)d_in[10];
    const float* Wr2_ui = (const float*)d_in[11];
    const float* b2_ui  = (const float*)d_in[12];
    const float* Wl2_iu = (const float*)d_in[13];
    const float* Wr2_iu = (const float*)d_in[14];
    const float* b2_iu  = (const float*)d_in[15];
    const int* uid  = (const int*)d_in[16];
    const int* esrc = (const int*)d_in[17];
    const int* edst = (const int*)d_in[18];
    const int* lsrc = (const int*)d_in[19];
    const int* ldst = (const int*)d_in[20];
    float* out = (float*)d_out;

    char* ws = (char*)d_ws;
    size_t off = 0;
    auto alloc = [&](size_t bytes) -> void* {
        void* p = ws + off;
        off += (bytes + 255) & ~(size_t)255;
        return p;
    };
    u16* xu_b   = (u16*)alloc((size_t)NUu * DDIM * 2);
    u16* hu1_b  = (u16*)alloc((size_t)NUu * DDIM * 2);
    u16* aggu_b = (u16*)alloc((size_t)NUu * DDIM * 2);   // also hu2
    u16* xi_b   = (u16*)alloc((size_t)NIi * DDIM * 2);
    u16* hi1_b  = (u16*)alloc((size_t)NIi * DDIM * 2);
    u16* aggi_b = (u16*)alloc((size_t)NIi * DDIM * 2);   // also hi2
    int* coli = (int*)alloc((size_t)NEe * 4);
    int* colu = (int*)alloc((size_t)NEe * 4);
    int* rpi  = (int*)alloc((size_t)(NIi + 1) * 4);
    int* rpu  = (int*)alloc((size_t)(NUu + 1) * 4);
    int* hist   = (int*)alloc((size_t)NBT * 4);
    int* base_i = (int*)alloc((size_t)(NB_I + 1) * 4);
    int* base_u = (int*)alloc((size_t)(NB_U + 1) * 4);
    int* fr_i   = (int*)alloc((size_t)NB_I * 4);
    int* fr_u   = (int*)alloc((size_t)NB_U * 4);
    u16* wbf    = (u16*)alloc((size_t)40 * 64 * 8 * 2);   // item W, frag order
    // scatter buffers alias xu_b (16 MB < 64 MB): CSR build runs before k_cast_users
    unsigned* scat_i = (unsigned*)xu_b;
    unsigned* scat_u = (unsigned*)((char*)xu_b + (size_t)NEe * 4);

    // ---- CSR build (bucketed) ----
    hipMemsetAsync(hist, 0, (size_t)NBT * 4, stream);
    int nchunks = (NEe + 2047) / 2048;   // 977
    k_hist<<<nchunks, 256, 0, stream>>>(esrc, edst, hist);
    k_bucket_scan<<<1, 256, 0, stream>>>(hist, base_i, fr_i, base_u, fr_u, rpi, rpu);
    k_scatter<<<nchunks, 256, 0, stream>>>(esrc, edst, fr_i, fr_u, scat_i, scat_u);
    k_bfill<<<NB_I, 256, 0, stream>>>(scat_i, base_i, rpi, coli, SH_I, BSZL_I, NIi);
    k_bfill<<<NB_U, 256, 0, stream>>>(scat_u, base_u, rpu, colu, SH_U, BSZL_U, NUu);

    // ---- input features (after CSR build: scat_* alias xu_b) ----
    k_cast_w<<<10, 256, 0, stream>>>(item_w, wbf);
    k_cast_users<<<NUu * 16 / 256, 256, 0, stream>>>(user_emb, uid, xu_b);
    k_item_lin2<<<512, 256, 0, stream>>>(item_x, wbf, item_b, xi_b);

    const int NT_I = NIi / 16;   // 6250
    const int NT_U = NUu / 16;   // 31250

    // layer 1
    k_agg<<<2048, 256, 0, stream>>>(xu_b, aggi_b, rpi, coli, NIi);
    k_transform<<<512, 256, 0, stream>>>(aggi_b, xi_b, Wl1_ui, Wr1_ui, b1_ui, hi1_b, NT_I, 1);
    k_agg<<<2048, 256, 0, stream>>>(xi_b, aggu_b, rpu, colu, NUu);
    k_transform<<<1024, 256, 0, stream>>>(aggu_b, xu_b, Wl1_iu, Wr1_iu, b1_iu, hu1_b, NT_U, 1);

    // layer 2 (hi2 aliases aggi_b, hu2 aliases aggu_b: per-tile read-before-write)
    k_agg<<<2048, 256, 0, stream>>>(hu1_b, aggi_b, rpi, coli, NIi);
    k_transform<<<512, 256, 0, stream>>>(aggi_b, hi1_b, Wl2_ui, Wr2_ui, b2_ui, aggi_b, NT_I, 0);
    k_agg<<<2048, 256, 0, stream>>>(hi1_b, aggu_b, rpu, colu, NUu);
    k_transform<<<1024, 256, 0, stream>>>(aggu_b, hu1_b, Wl2_iu, Wr2_iu, b2_iu, aggu_b, NT_U, 0);

    // predictor
    k_dot<<<2048, 256, 0, stream>>>(aggu_b, aggi_b, lsrc, ldst, out);
}